// Round 1
// baseline (1348.835 us; speedup 1.0000x reference)
//
#include <hip/hip_runtime.h>
#include <hip/hip_bf16.h>

#define N_NODES 100000
#define N_EDGES 1250000

static __device__ __forceinline__ float bf2f(unsigned short u) {
    union { unsigned int i; float f; } v; v.i = ((unsigned int)u) << 16; return v.f;
}
static __device__ __forceinline__ unsigned short f2bf(float f) {
    union { float f; unsigned int i; } v; v.f = f;
    unsigned int x = v.i;
    return (unsigned short)((x + 0x7FFFu + ((x >> 16) & 1u)) >> 16); // RNE
}

// M[d][k] layout [64][128]: k<64 -> (W1-W2)[d][k], k>=64 -> W2[d][k-64]
__global__ __launch_bounds__(256) void prep_M(const float* __restrict__ W,
                                              float* __restrict__ M) {
    int t = blockIdx.x * 256 + threadIdx.x;
    if (t >= 64 * 128) return;
    int d = t >> 7, k = t & 127;
    float v;
    if (k < 64) v = W[d * 64 + k] - W[(d + 64) * 64 + k];
    else        v = W[(d + 64) * 64 + (k - 64)];
    M[d * 128 + k] = v;
}

// int64-vs-int32 edge_index detector: if dtype is int64 (little-endian, values
// < 2^17, nonnegative), every odd int32 word is 0. Sample 1024 of them.
__global__ void detect64(const int* __restrict__ ei, unsigned int* __restrict__ flag) {
    int t = blockIdx.x * 256 + threadIdx.x; // 1024 threads
    if (ei[2 * t + 1] != 0) atomicOr(flag, 1u);
}

// One thread per node: y1[n] = x[n] @ (W1-W2) + b ; y2[n] = x[n] @ W2, bf16 out.
__global__ __launch_bounds__(256) void node_transform(
    const float* __restrict__ x, const float* __restrict__ M,
    const float* __restrict__ b,
    unsigned short* __restrict__ y1, unsigned short* __restrict__ y2)
{
    int n = blockIdx.x * 256 + threadIdx.x;
    if (n >= N_NODES) return;
    float xr[64];
    const float4* xv = (const float4*)(x + (size_t)n * 64);
    #pragma unroll
    for (int i = 0; i < 16; ++i) {
        float4 v = xv[i];
        xr[4 * i + 0] = v.x; xr[4 * i + 1] = v.y;
        xr[4 * i + 2] = v.z; xr[4 * i + 3] = v.w;
    }
    #pragma unroll 1
    for (int kc = 0; kc < 8; ++kc) {
        float acc[16];
        #pragma unroll
        for (int kk = 0; kk < 16; ++kk)
            acc[kk] = (kc < 4) ? b[kc * 16 + kk] : 0.0f;
        const float* Mc = M + kc * 16; // uniform address -> scalar loads
        #pragma unroll
        for (int d = 0; d < 64; ++d) {
            #pragma unroll
            for (int kk = 0; kk < 16; ++kk)
                acc[kk] = fmaf(xr[d], Mc[d * 128 + kk], acc[kk]);
        }
        unsigned int u[8];
        #pragma unroll
        for (int p = 0; p < 8; ++p)
            u[p] = (unsigned int)f2bf(acc[2 * p]) |
                   ((unsigned int)f2bf(acc[2 * p + 1]) << 16);
        unsigned short* yp = (kc < 4) ? (y1 + (size_t)n * 64 + kc * 16)
                                      : (y2 + (size_t)n * 64 + (kc - 4) * 16);
        uint4* o = (uint4*)yp;
        o[0] = make_uint4(u[0], u[1], u[2], u[3]);
        o[1] = make_uint4(u[4], u[5], u[6], u[7]);
    }
}

// 16 lanes per edge; each lane handles 4 of the 64 output features.
__global__ __launch_bounds__(256) void edge_kernel(
    const int* __restrict__ ei,
    const unsigned short* __restrict__ y1, const unsigned short* __restrict__ y2,
    float* __restrict__ out, float* __restrict__ cnt,
    const unsigned int* __restrict__ flag)
{
    int gid = blockIdx.x * 256 + threadIdx.x;
    int e = gid >> 4;
    if (e >= N_EDGES) return;
    int q = gid & 15;
    bool is64 = (*flag == 0u);
    int j, i;
    if (is64) { j = ei[2 * e];  i = ei[2 * (N_EDGES + e)]; }   // int64 low words
    else      { j = ei[e];      i = ei[N_EDGES + e]; }
    ushort4 a = *(const ushort4*)(y1 + (size_t)i * 64 + q * 4);
    ushort4 c = *(const ushort4*)(y2 + (size_t)j * 64 + q * 4);
    float h0 = fmaxf(bf2f(a.x) + bf2f(c.x), 0.0f);
    float h1 = fmaxf(bf2f(a.y) + bf2f(c.y), 0.0f);
    float h2 = fmaxf(bf2f(a.z) + bf2f(c.z), 0.0f);
    float h3 = fmaxf(bf2f(a.w) + bf2f(c.w), 0.0f);
    float* o = out + (size_t)i * 64 + q * 4;
    unsafeAtomicAdd(o + 0, h0);
    unsafeAtomicAdd(o + 1, h1);
    unsafeAtomicAdd(o + 2, h2);
    unsafeAtomicAdd(o + 3, h3);
    if (q == 0) unsafeAtomicAdd(&cnt[i], 1.0f);
}

__global__ __launch_bounds__(256) void finalize(float* __restrict__ out,
                                                const float* __restrict__ cnt) {
    int t = blockIdx.x * 256 + threadIdx.x;
    int n = t >> 4;
    if (n >= N_NODES) return;
    float inv = 1.0f / fmaxf(cnt[n], 1.0f);
    float4* p = (float4*)(out + (size_t)n * 64) + (t & 15);
    float4 v = *p;
    v.x *= inv; v.y *= inv; v.z *= inv; v.w *= inv;
    *p = v;
}

extern "C" void kernel_launch(void* const* d_in, const int* in_sizes, int n_in,
                              void* d_out, int out_size, void* d_ws, size_t ws_size,
                              hipStream_t stream) {
    const float* x = (const float*)d_in[0];
    const int*   ei = (const int*)d_in[1];
    const float* W = (const float*)d_in[2];
    const float* b = (const float*)d_in[3];
    float* out = (float*)d_out;

    char* ws = (char*)d_ws;
    float* M            = (float*)(ws);                         // 32 KB
    float* cnt          = (float*)(ws + 64 * 1024);             // 400 KB
    unsigned int* flag  = (unsigned int*)(ws + 512 * 1024);     // 4 B
    unsigned short* y1  = (unsigned short*)(ws + 1024 * 1024);  // 12.8 MB
    unsigned short* y2  = (unsigned short*)(ws + 16u * 1024 * 1024); // 12.8 MB
    // total ws need: 16 MB + 12.8 MB = 28.8 MB

    hipMemsetAsync(out, 0, (size_t)N_NODES * 64 * sizeof(float), stream);
    hipMemsetAsync(cnt, 0, N_NODES * sizeof(float), stream);
    hipMemsetAsync(flag, 0, sizeof(unsigned int), stream);

    prep_M<<<32, 256, 0, stream>>>(W, M);
    detect64<<<4, 256, 0, stream>>>(ei, flag);
    node_transform<<<(N_NODES + 255) / 256, 256, 0, stream>>>(x, M, b, y1, y2);
    edge_kernel<<<(N_EDGES * 16 + 255) / 256, 256, 0, stream>>>(ei, y1, y2, out, cnt, flag);
    finalize<<<(N_NODES * 16 + 255) / 256, 256, 0, stream>>>(out, cnt);
}

// Round 2
// 405.615 us; speedup vs baseline: 3.3254x; 3.3254x over previous
//
#include <hip/hip_runtime.h>
#include <hip/hip_bf16.h>

#define N_NODES 100000
#define N_EDGES 1250000
#define NBLK ((N_NODES + 255) / 256)   // 391 scan blocks

static __device__ __forceinline__ float bf2f(unsigned short u) {
    union { unsigned int i; float f; } v; v.i = ((unsigned int)u) << 16; return v.f;
}
static __device__ __forceinline__ unsigned short f2bf(float f) {
    union { float f; unsigned int i; } v; v.f = f;
    unsigned int x = v.i;
    return (unsigned short)((x + 0x7FFFu + ((x >> 16) & 1u)) >> 16); // RNE
}

// M[d][k] layout [64][128]: k<64 -> (W1-W2)[d][k], k>=64 -> W2[d][k-64]
__global__ __launch_bounds__(256) void prep_M(const float* __restrict__ W,
                                              float* __restrict__ M) {
    int t = blockIdx.x * 256 + threadIdx.x;
    if (t >= 64 * 128) return;
    int d = t >> 7, k = t & 127;
    float v;
    if (k < 64) v = W[d * 64 + k] - W[(d + 64) * 64 + k];
    else        v = W[(d + 64) * 64 + (k - 64)];
    M[d * 128 + k] = v;
}

// int64-vs-int32 detector: for int64 (values < 2^17), every odd word is 0.
__global__ void detect64(const int* __restrict__ ei, unsigned int* __restrict__ flag) {
    int t = blockIdx.x * 256 + threadIdx.x; // 1024 threads
    if (ei[2 * t + 1] != 0) atomicOr(flag, 1u);
}

// One thread per node: y1[n] = x[n]@(W1-W2) + b ; y2[n] = x[n]@W2, bf16 out.
__global__ __launch_bounds__(256) void node_transform(
    const float* __restrict__ x, const float* __restrict__ M,
    const float* __restrict__ b,
    unsigned short* __restrict__ y1, unsigned short* __restrict__ y2)
{
    int n = blockIdx.x * 256 + threadIdx.x;
    if (n >= N_NODES) return;
    float xr[64];
    const float4* xv = (const float4*)(x + (size_t)n * 64);
    #pragma unroll
    for (int i = 0; i < 16; ++i) {
        float4 v = xv[i];
        xr[4 * i + 0] = v.x; xr[4 * i + 1] = v.y;
        xr[4 * i + 2] = v.z; xr[4 * i + 3] = v.w;
    }
    #pragma unroll 1
    for (int kc = 0; kc < 8; ++kc) {
        float acc[16];
        #pragma unroll
        for (int kk = 0; kk < 16; ++kk)
            acc[kk] = (kc < 4) ? b[kc * 16 + kk] : 0.0f;
        const float* Mc = M + kc * 16; // uniform address -> scalar loads
        #pragma unroll
        for (int d = 0; d < 64; ++d) {
            #pragma unroll
            for (int kk = 0; kk < 16; ++kk)
                acc[kk] = fmaf(xr[d], Mc[d * 128 + kk], acc[kk]);
        }
        unsigned int u[8];
        #pragma unroll
        for (int p = 0; p < 8; ++p)
            u[p] = (unsigned int)f2bf(acc[2 * p]) |
                   ((unsigned int)f2bf(acc[2 * p + 1]) << 16);
        unsigned short* yp = (kc < 4) ? (y1 + (size_t)n * 64 + kc * 16)
                                      : (y2 + (size_t)n * 64 + (kc - 4) * 16);
        uint4* o = (uint4*)yp;
        o[0] = make_uint4(u[0], u[1], u[2], u[3]);
        o[1] = make_uint4(u[4], u[5], u[6], u[7]);
    }
}

// ---- CSR build: histogram -> scan -> scatter ------------------------------

__global__ __launch_bounds__(256) void hist_kernel(
    const int* __restrict__ ei, const unsigned int* __restrict__ flag,
    int* __restrict__ deg)
{
    int e = blockIdx.x * 256 + threadIdx.x;
    if (e >= N_EDGES) return;
    bool is64 = (*flag == 0u);
    int i = is64 ? ei[2 * (N_EDGES + e)] : ei[N_EDGES + e];
    atomicAdd(&deg[i], 1);
}

// Block-local exclusive scan; block sums to partials.
__global__ __launch_bounds__(256) void scan_part(
    const int* __restrict__ deg, int* __restrict__ row_start,
    int* __restrict__ partials)
{
    __shared__ int s[256];
    int tid = threadIdx.x;
    int gid = blockIdx.x * 256 + tid;
    int v = (gid < N_NODES) ? deg[gid] : 0;
    s[tid] = v; __syncthreads();
    #pragma unroll
    for (int off = 1; off < 256; off <<= 1) {
        int t = (tid >= off) ? s[tid - off] : 0;
        __syncthreads();
        s[tid] += t;
        __syncthreads();
    }
    if (gid < N_NODES) row_start[gid] = s[tid] - v; // block-local exclusive
    if (tid == 255) partials[blockIdx.x] = s[255];
}

// Single block scans the 391 partial sums (exclusive, in place).
__global__ __launch_bounds__(512) void scan_top(int* __restrict__ partials) {
    __shared__ int s[512];
    int tid = threadIdx.x;
    int v = (tid < NBLK) ? partials[tid] : 0;
    s[tid] = v; __syncthreads();
    #pragma unroll
    for (int off = 1; off < 512; off <<= 1) {
        int t = (tid >= off) ? s[tid - off] : 0;
        __syncthreads();
        s[tid] += t;
        __syncthreads();
    }
    if (tid < NBLK) partials[tid] = s[tid] - v; // exclusive
}

__global__ __launch_bounds__(256) void scan_add(
    int* __restrict__ row_start, const int* __restrict__ partials,
    int* __restrict__ cursor)
{
    int gid = blockIdx.x * 256 + threadIdx.x;
    if (gid >= N_NODES) return;
    int v = row_start[gid] + partials[blockIdx.x];
    row_start[gid] = v;
    cursor[gid] = v;
}

__global__ __launch_bounds__(256) void scatter_kernel(
    const int* __restrict__ ei, const unsigned int* __restrict__ flag,
    int* __restrict__ cursor, int* __restrict__ csr)
{
    int e = blockIdx.x * 256 + threadIdx.x;
    if (e >= N_EDGES) return;
    bool is64 = (*flag == 0u);
    int j, i;
    if (is64) { j = ei[2 * e];  i = ei[2 * (N_EDGES + e)]; }
    else      { j = ei[e];      i = ei[N_EDGES + e]; }
    int pos = atomicAdd(&cursor[i], 1);
    csr[pos] = j;
}

// ---- Gather: 16 lanes per node, accumulate relu(y1[i]+y2[j]) in regs ------
__global__ __launch_bounds__(256) void gather_kernel(
    const int* __restrict__ row_start, const int* __restrict__ row_end,
    const int* __restrict__ csr,
    const unsigned short* __restrict__ y1, const unsigned short* __restrict__ y2,
    float* __restrict__ out)
{
    int gid = blockIdx.x * 256 + threadIdx.x;
    int n = gid >> 4;
    if (n >= N_NODES) return;
    int q = gid & 15;
    int lane = threadIdx.x & 63;
    int lbase = lane & 48; // first lane of this 16-lane group within the wave

    int rs = row_start[n];
    int re = row_end[n];   // cursor after scatter == row end

    ushort4 a = *(const ushort4*)(y1 + (size_t)n * 64 + q * 4);
    float a0 = bf2f(a.x), a1 = bf2f(a.y), a2 = bf2f(a.z), a3 = bf2f(a.w);
    float s0 = 0.f, s1 = 0.f, s2 = 0.f, s3 = 0.f;

    int p = rs;
    // full batches of 16 edges: lane q preloads csr[p+q], broadcast via shfl
    while (p + 16 <= re) {
        int myj = csr[p + q];
        #pragma unroll
        for (int k = 0; k < 16; ++k) {
            int j = __shfl(myj, lbase + k, 64);
            ushort4 c = *(const ushort4*)(y2 + (size_t)j * 64 + q * 4);
            s0 += fmaxf(a0 + bf2f(c.x), 0.0f);
            s1 += fmaxf(a1 + bf2f(c.y), 0.0f);
            s2 += fmaxf(a2 + bf2f(c.z), 0.0f);
            s3 += fmaxf(a3 + bf2f(c.w), 0.0f);
        }
        p += 16;
    }
    // tail (most nodes: deg ~ Poisson(12.5))
    int m = re - p;
    int myj = (q < m) ? csr[p + q] : 0;
    #pragma unroll 4
    for (int k = 0; k < m; ++k) {
        int j = __shfl(myj, lbase + k, 64);
        ushort4 c = *(const ushort4*)(y2 + (size_t)j * 64 + q * 4);
        s0 += fmaxf(a0 + bf2f(c.x), 0.0f);
        s1 += fmaxf(a1 + bf2f(c.y), 0.0f);
        s2 += fmaxf(a2 + bf2f(c.z), 0.0f);
        s3 += fmaxf(a3 + bf2f(c.w), 0.0f);
    }

    float inv = 1.0f / fmaxf((float)(re - rs), 1.0f);
    float4 o = make_float4(s0 * inv, s1 * inv, s2 * inv, s3 * inv);
    *((float4*)(out + (size_t)n * 64) + q) = o;
}

extern "C" void kernel_launch(void* const* d_in, const int* in_sizes, int n_in,
                              void* d_out, int out_size, void* d_ws, size_t ws_size,
                              hipStream_t stream) {
    const float* x = (const float*)d_in[0];
    const int*   ei = (const int*)d_in[1];
    const float* W = (const float*)d_in[2];
    const float* b = (const float*)d_in[3];
    float* out = (float*)d_out;

    char* ws = (char*)d_ws;
    float*        M        = (float*)(ws);                    // 32 KB
    unsigned int* flag     = (unsigned int*)(ws + 32768);     // 4 B
    int*          partials = (int*)(ws + 40960);              // 1.6 KB
    int*          deg      = (int*)(ws + 65536);              // 400 KB
    int*          row_start= (int*)(ws + 465536);             // 400 KB
    int*          cursor   = (int*)(ws + 865536);             // 400 KB
    int*          csr      = (int*)(ws + 1265536);            // 5 MB
    unsigned short* y1     = (unsigned short*)(ws + 6265536); // 12.8 MB
    unsigned short* y2     = (unsigned short*)(ws + 19065536);// 12.8 MB  (end ~30.4 MB)

    hipMemsetAsync(flag, 0, sizeof(unsigned int), stream);
    hipMemsetAsync(deg, 0, N_NODES * sizeof(int), stream);

    prep_M<<<32, 256, 0, stream>>>(W, M);
    detect64<<<4, 256, 0, stream>>>(ei, flag);
    node_transform<<<(N_NODES + 255) / 256, 256, 0, stream>>>(x, M, b, y1, y2);
    hist_kernel<<<(N_EDGES + 255) / 256, 256, 0, stream>>>(ei, flag, deg);
    scan_part<<<NBLK, 256, 0, stream>>>(deg, row_start, partials);
    scan_top<<<1, 512, 0, stream>>>(partials);
    scan_add<<<NBLK, 256, 0, stream>>>(row_start, partials, cursor);
    scatter_kernel<<<(N_EDGES + 255) / 256, 256, 0, stream>>>(ei, flag, cursor, csr);
    gather_kernel<<<(N_NODES * 16 + 255) / 256, 256, 0, stream>>>(
        row_start, cursor, csr, y1, y2, out);
}

// Round 3
// 289.121 us; speedup vs baseline: 4.6653x; 1.4029x over previous
//
#include <hip/hip_runtime.h>
#include <hip/hip_bf16.h>

#define N_NODES 100000
#define N_EDGES 1250000
#define NBLK ((N_NODES + 255) / 256)   // 391 scan blocks

typedef float f32x4 __attribute__((ext_vector_type(4)));
typedef short bf16x8 __attribute__((ext_vector_type(8)));

static __device__ __forceinline__ float bf2f(unsigned short u) {
    union { unsigned int i; float f; } v; v.i = ((unsigned int)u) << 16; return v.f;
}
static __device__ __forceinline__ unsigned short f2bf(float f) {
    union { float f; unsigned int i; } v; v.f = f;
    unsigned int x = v.i;
    return (unsigned short)((x + 0x7FFFu + ((x >> 16) & 1u)) >> 16); // RNE
}

// ---- Prep: pack M = [W1-W2 | W2] directly into MFMA B-fragments (bf16) ----
// Frag f = c*2 + s (c = 16-col output chunk 0..7, s = K-step 0..1).
// Lane l, elem j holds B[k = (l>>4)*8 + j + 32*s][col = c*16 + (l&15)].
// Stored contiguously: Bfrag[f*512 + l*8 + j] -> one uint4 load per lane.
__global__ __launch_bounds__(256) void prep_frags(const float* __restrict__ W,
                                                  unsigned short* __restrict__ Bfrag) {
    int t = blockIdx.x * 256 + threadIdx.x;
    if (t >= 8192) return;
    int f = t >> 9;
    int l = (t >> 3) & 63;
    int j = t & 7;
    int c = f >> 1, s = f & 1;
    int d = ((l >> 4) << 3) + j + 32 * s;   // K index (input dim) 0..63
    int kcol = c * 16 + (l & 15);           // output col 0..127
    float v = (kcol < 64) ? (W[d * 64 + kcol] - W[(d + 64) * 64 + kcol])
                          : W[(d + 64) * 64 + (kcol - 64)];
    Bfrag[(size_t)f * 512 + l * 8 + j] = f2bf(v);
}

// int64-vs-int32 detector: for int64 (values < 2^17), every odd word is 0.
__global__ void detect64(const int* __restrict__ ei, unsigned int* __restrict__ flag) {
    int t = blockIdx.x * 256 + threadIdx.x; // 1024 threads
    if (ei[2 * t + 1] != 0) atomicOr(flag, 1u);
}

// ---- Node transform via MFMA: y_cat[100K x 128] = x[100K x 64] @ M --------
// One wave = 16 nodes x 128 cols. 8 C-frags x 2 K-steps = 16 MFMAs.
__global__ __launch_bounds__(256) void node_mfma(
    const float* __restrict__ x, const unsigned short* __restrict__ Bfrag,
    const float* __restrict__ b,
    unsigned short* __restrict__ y1, unsigned short* __restrict__ y2)
{
    int wid = (blockIdx.x * 256 + threadIdx.x) >> 6;
    int base = wid * 16;
    if (base >= N_NODES) return;
    int l = threadIdx.x & 63;
    int lo16 = l & 15, grp = l >> 4;

    // All 16 B-frags (L1-hot, 1 KB each, coalesced)
    bf16x8 bf[16];
    const uint4* bp = (const uint4*)Bfrag;
    #pragma unroll
    for (int f = 0; f < 16; ++f) {
        union { uint4 u; bf16x8 s; } cv;
        cv.u = bp[f * 64 + l];
        bf[f] = cv.s;
    }

    // A-frags from x (fp32 -> bf16): lane holds x[base+lo16][grp*8 + j + 32s]
    const float* xp = x + (size_t)(base + lo16) * 64 + (grp << 3);
    bf16x8 afr[2];
    #pragma unroll
    for (int s = 0; s < 2; ++s) {
        float4 v0 = *(const float4*)(xp + 32 * s);
        float4 v1 = *(const float4*)(xp + 32 * s + 4);
        bf16x8 a;
        a[0] = (short)f2bf(v0.x); a[1] = (short)f2bf(v0.y);
        a[2] = (short)f2bf(v0.z); a[3] = (short)f2bf(v0.w);
        a[4] = (short)f2bf(v1.x); a[5] = (short)f2bf(v1.y);
        a[6] = (short)f2bf(v1.z); a[7] = (short)f2bf(v1.w);
        afr[s] = a;
    }

    // Accumulators: bias for y1 chunks (col-determined -> same across rows)
    f32x4 acc[8];
    #pragma unroll
    for (int c = 0; c < 8; ++c) {
        float bias = (c < 4) ? b[c * 16 + lo16] : 0.0f;
        acc[c] = (f32x4){bias, bias, bias, bias};
    }

    #pragma unroll
    for (int c = 0; c < 8; ++c) {
        acc[c] = __builtin_amdgcn_mfma_f32_16x16x32_bf16(afr[0], bf[c * 2 + 0], acc[c], 0, 0, 0);
        acc[c] = __builtin_amdgcn_mfma_f32_16x16x32_bf16(afr[1], bf[c * 2 + 1], acc[c], 0, 0, 0);
    }

    // D layout: lane holds D[row = grp*4 + r][col = lo16] per chunk c.
    #pragma unroll
    for (int c = 0; c < 8; ++c) {
        unsigned short* yp = (c < 4) ? y1 : y2;
        int colbase = (c & 3) * 16 + lo16;
        #pragma unroll
        for (int r = 0; r < 4; ++r) {
            int node = base + grp * 4 + r;
            yp[(size_t)node * 64 + colbase] = f2bf(acc[c][r]);
        }
    }
}

// ---- CSR build: histogram -> scan -> scatter ------------------------------

__global__ __launch_bounds__(256) void hist_kernel(
    const int* __restrict__ ei, const unsigned int* __restrict__ flag,
    int* __restrict__ deg)
{
    int e = blockIdx.x * 256 + threadIdx.x;
    if (e >= N_EDGES) return;
    bool is64 = (*flag == 0u);
    int i = is64 ? ei[2 * (N_EDGES + e)] : ei[N_EDGES + e];
    atomicAdd(&deg[i], 1);
}

__global__ __launch_bounds__(256) void scan_part(
    const int* __restrict__ deg, int* __restrict__ row_start,
    int* __restrict__ partials)
{
    __shared__ int s[256];
    int tid = threadIdx.x;
    int gid = blockIdx.x * 256 + tid;
    int v = (gid < N_NODES) ? deg[gid] : 0;
    s[tid] = v; __syncthreads();
    #pragma unroll
    for (int off = 1; off < 256; off <<= 1) {
        int t = (tid >= off) ? s[tid - off] : 0;
        __syncthreads();
        s[tid] += t;
        __syncthreads();
    }
    if (gid < N_NODES) row_start[gid] = s[tid] - v;
    if (tid == 255) partials[blockIdx.x] = s[255];
}

__global__ __launch_bounds__(512) void scan_top(int* __restrict__ partials) {
    __shared__ int s[512];
    int tid = threadIdx.x;
    int v = (tid < NBLK) ? partials[tid] : 0;
    s[tid] = v; __syncthreads();
    #pragma unroll
    for (int off = 1; off < 512; off <<= 1) {
        int t = (tid >= off) ? s[tid - off] : 0;
        __syncthreads();
        s[tid] += t;
        __syncthreads();
    }
    if (tid < NBLK) partials[tid] = s[tid] - v;
}

__global__ __launch_bounds__(256) void scan_add(
    int* __restrict__ row_start, const int* __restrict__ partials,
    int* __restrict__ cursor)
{
    int gid = blockIdx.x * 256 + threadIdx.x;
    if (gid >= N_NODES) return;
    int v = row_start[gid] + partials[blockIdx.x];
    row_start[gid] = v;
    cursor[gid] = v;
}

__global__ __launch_bounds__(256) void scatter_kernel(
    const int* __restrict__ ei, const unsigned int* __restrict__ flag,
    int* __restrict__ cursor, int* __restrict__ csr)
{
    int e = blockIdx.x * 256 + threadIdx.x;
    if (e >= N_EDGES) return;
    bool is64 = (*flag == 0u);
    int j, i;
    if (is64) { j = ei[2 * e];  i = ei[2 * (N_EDGES + e)]; }
    else      { j = ei[e];      i = ei[N_EDGES + e]; }
    int pos = atomicAdd(&cursor[i], 1);
    csr[pos] = j;
}

// ---- Gather: 16 lanes per node, accumulate relu(y1[i]+y2[j]) in regs ------
__global__ __launch_bounds__(256) void gather_kernel(
    const int* __restrict__ row_start, const int* __restrict__ row_end,
    const int* __restrict__ csr,
    const unsigned short* __restrict__ y1, const unsigned short* __restrict__ y2,
    float* __restrict__ out)
{
    int gid = blockIdx.x * 256 + threadIdx.x;
    int n = gid >> 4;
    if (n >= N_NODES) return;
    int q = gid & 15;
    int lane = threadIdx.x & 63;
    int lbase = lane & 48;

    int rs = row_start[n];
    int re = row_end[n];

    ushort4 a = *(const ushort4*)(y1 + (size_t)n * 64 + q * 4);
    float a0 = bf2f(a.x), a1 = bf2f(a.y), a2 = bf2f(a.z), a3 = bf2f(a.w);
    float s0 = 0.f, s1 = 0.f, s2 = 0.f, s3 = 0.f;

    int p = rs;
    while (p + 16 <= re) {
        int myj = csr[p + q];
        #pragma unroll
        for (int k = 0; k < 16; ++k) {
            int j = __shfl(myj, lbase + k, 64);
            ushort4 c = *(const ushort4*)(y2 + (size_t)j * 64 + q * 4);
            s0 += fmaxf(a0 + bf2f(c.x), 0.0f);
            s1 += fmaxf(a1 + bf2f(c.y), 0.0f);
            s2 += fmaxf(a2 + bf2f(c.z), 0.0f);
            s3 += fmaxf(a3 + bf2f(c.w), 0.0f);
        }
        p += 16;
    }
    int m = re - p;
    int myj = (q < m) ? csr[p + q] : 0;
    #pragma unroll 4
    for (int k = 0; k < m; ++k) {
        int j = __shfl(myj, lbase + k, 64);
        ushort4 c = *(const ushort4*)(y2 + (size_t)j * 64 + q * 4);
        s0 += fmaxf(a0 + bf2f(c.x), 0.0f);
        s1 += fmaxf(a1 + bf2f(c.y), 0.0f);
        s2 += fmaxf(a2 + bf2f(c.z), 0.0f);
        s3 += fmaxf(a3 + bf2f(c.w), 0.0f);
    }

    float inv = 1.0f / fmaxf((float)(re - rs), 1.0f);
    float4 o = make_float4(s0 * inv, s1 * inv, s2 * inv, s3 * inv);
    *((float4*)(out + (size_t)n * 64) + q) = o;
}

extern "C" void kernel_launch(void* const* d_in, const int* in_sizes, int n_in,
                              void* d_out, int out_size, void* d_ws, size_t ws_size,
                              hipStream_t stream) {
    const float* x = (const float*)d_in[0];
    const int*   ei = (const int*)d_in[1];
    const float* W = (const float*)d_in[2];
    const float* b = (const float*)d_in[3];
    float* out = (float*)d_out;

    char* ws = (char*)d_ws;
    unsigned short* Bfrag  = (unsigned short*)(ws);           // 16 KB
    unsigned int* flag     = (unsigned int*)(ws + 32768);     // 4 B
    int*          partials = (int*)(ws + 40960);              // 1.6 KB
    int*          deg      = (int*)(ws + 65536);              // 400 KB
    int*          row_start= (int*)(ws + 465536);             // 400 KB
    int*          cursor   = (int*)(ws + 865536);             // 400 KB
    int*          csr      = (int*)(ws + 1265536);            // 5 MB
    unsigned short* y1     = (unsigned short*)(ws + 6265536); // 12.8 MB
    unsigned short* y2     = (unsigned short*)(ws + 19065536);// 12.8 MB  (end ~30.4 MB)

    hipMemsetAsync(flag, 0, sizeof(unsigned int), stream);
    hipMemsetAsync(deg, 0, N_NODES * sizeof(int), stream);

    prep_frags<<<32, 256, 0, stream>>>(W, Bfrag);
    detect64<<<4, 256, 0, stream>>>(ei, flag);
    node_mfma<<<(N_NODES / 16 + 3) / 4, 256, 0, stream>>>(x, Bfrag, b, y1, y2);
    hist_kernel<<<(N_EDGES + 255) / 256, 256, 0, stream>>>(ei, flag, deg);
    scan_part<<<NBLK, 256, 0, stream>>>(deg, row_start, partials);
    scan_top<<<1, 512, 0, stream>>>(partials);
    scan_add<<<NBLK, 256, 0, stream>>>(row_start, partials, cursor);
    scatter_kernel<<<(N_EDGES + 255) / 256, 256, 0, stream>>>(ei, flag, cursor, csr);
    gather_kernel<<<(N_NODES * 16 + 255) / 256, 256, 0, stream>>>(
        row_start, cursor, csr, y1, y2, out);
}